// Round 8
// baseline (357.671 us; speedup 1.0000x reference)
//
#include <hip/hip_runtime.h>
#include <hip/hip_bf16.h>
#include <stdint.h>

#define D_MODEL 512
#define N_EXP 8
#define D_FF 2048
#define NTOK 8192
#define TM 256
#define MAX_TILES 72                 /* ceil(16384/256) + 8 */
#define NEPAD (MAX_TILES*TM)         /* 18432 */

typedef __attribute__((ext_vector_type(8))) short short8;
typedef __attribute__((ext_vector_type(4))) float f32x4;

struct Ctrl {
  int cnt[8];
  int cursor[8];
  int offpad[16];
  int ntiles;
  int pad[3];
  int texp[MAX_TILES];
};

__device__ __forceinline__ unsigned short f2bf(float f){
  unsigned u = __float_as_uint(f);
  u += 0x7FFFu + ((u>>16)&1u);          // RNE
  return (unsigned short)(u>>16);
}
__device__ __forceinline__ float bf2f(unsigned short v){
  return __uint_as_float(((unsigned)v)<<16);
}

__device__ __forceinline__ short8 pack8(float4 a, float4 b){
  short8 o;
  o[0]=(short)f2bf(a.x); o[1]=(short)f2bf(a.y); o[2]=(short)f2bf(a.z); o[3]=(short)f2bf(a.w);
  o[4]=(short)f2bf(b.x); o[5]=(short)f2bf(b.y); o[6]=(short)f2bf(b.z); o[7]=(short)f2bf(b.w);
  return o;
}

__device__ __forceinline__ void gload16(const void* g, void* l){
  __builtin_amdgcn_global_load_lds((const __attribute__((address_space(1))) unsigned int*)g,
                                   (__attribute__((address_space(3))) unsigned int*)l, 16, 0, 0);
}

#define SBAR0 __builtin_amdgcn_sched_barrier(0)
#define BAR   do{ SBAR0; __builtin_amdgcn_s_barrier(); SBAR0; }while(0)
#define VM(N) do{ asm volatile("s_waitcnt vmcnt(" #N ")" ::: "memory"); SBAR0; }while(0)

// ---------------- f32 -> bf16 (up to 3 tensors in one launch) ----------------
__global__ void __launch_bounds__(256)
cvt3_kernel(const float* __restrict__ s0, const float* __restrict__ s1, const float* __restrict__ s2,
            unsigned short* __restrict__ d0, unsigned short* __restrict__ d1, unsigned short* __restrict__ d2){
  const float* src = (blockIdx.y==0) ? s0 : (blockIdx.y==1 ? s1 : s2);
  unsigned short* dst = (blockIdx.y==0) ? d0 : (blockIdx.y==1 ? d1 : d2);
  int i = (blockIdx.x*256 + threadIdx.x)*8;
  float4 a = *(const float4*)(src+i);
  float4 b = *(const float4*)(src+i+4);
  *(short8*)(dst+i) = pack8(a,b);
}

__global__ void __launch_bounds__(256)
cvt_kernel(const float* __restrict__ src, unsigned short* __restrict__ dst, int n){
  int i = (blockIdx.x*256 + threadIdx.x)*8;
  if(i >= n) return;
  float4 a = *(const float4*)(src+i);
  float4 b = *(const float4*)(src+i+4);
  *(short8*)(dst+i) = pack8(a,b);
}

// ---------------- gating: logits->softmax->top2 (+x->bf16) ----------------
__global__ void __launch_bounds__(256)
gate_kernel(const float* __restrict__ x, const float* __restrict__ gw,
            int* __restrict__ tok_e, float* __restrict__ tok_s,
            Ctrl* __restrict__ c, float* __restrict__ Ppart,
            unsigned short* __restrict__ Xb){
  __shared__ float gws[N_EXP*D_MODEL];
  __shared__ float pblk[4][8];
  __shared__ int cblk[8];
  int tid = threadIdx.x;
  for(int i=tid; i<N_EXP*D_MODEL; i+=256) gws[i]=gw[i];
  if(tid<8) cblk[tid]=0;
  __syncthreads();
  int wave = tid>>6, lane = tid&63;
  int t = blockIdx.x*4 + wave;
  const float* xr = x + (size_t)t*D_MODEL + lane*8;
  float4 xa = *(const float4*)xr;
  float4 xb = *(const float4*)(xr+4);
  *(short8*)(Xb + (size_t)t*D_MODEL + lane*8) = pack8(xa,xb);
  float le[8];
  #pragma unroll
  for(int e=0;e<8;e++){
    const float* g = gws + e*D_MODEL + lane*8;
    float4 ga = *(const float4*)g;
    float4 gb = *(const float4*)(g+4);
    le[e] = xa.x*ga.x + xa.y*ga.y + xa.z*ga.z + xa.w*ga.w
          + xb.x*gb.x + xb.y*gb.y + xb.z*gb.z + xb.w*gb.w;
  }
  #pragma unroll
  for(int e=0;e<8;e++){
    float v = le[e];
    #pragma unroll
    for(int off=1; off<64; off<<=1) v += __shfl_xor(v, off);
    le[e]=v;
  }
  float mx = le[0];
  #pragma unroll
  for(int e=1;e<8;e++) mx = fmaxf(mx, le[e]);
  float p[8], s=0.f;
  #pragma unroll
  for(int e=0;e<8;e++){ p[e]=__expf(le[e]-mx); s+=p[e]; }
  float inv = 1.0f/s;
  #pragma unroll
  for(int e=0;e<8;e++) p[e]*=inv;
  int e0=0; float s0=p[0];
  #pragma unroll
  for(int e=1;e<8;e++) if(p[e]>s0){e0=e;s0=p[e];}
  int e1=-1; float s1=-1.f;
  #pragma unroll
  for(int e=0;e<8;e++) if(e!=e0 && p[e]>s1){e1=e;s1=p[e];}
  if(lane==0){
    tok_e[2*t]=e0; tok_e[2*t+1]=e1;
    tok_s[2*t]=s0; tok_s[2*t+1]=s1;
    atomicAdd(&cblk[e0],1); atomicAdd(&cblk[e1],1);
    #pragma unroll
    for(int e=0;e<8;e++) pblk[wave][e]=p[e];
  }
  __syncthreads();
  if(tid<8){
    atomicAdd(&c->cnt[tid], cblk[tid]);
    Ppart[blockIdx.x*8+tid] = pblk[0][tid]+pblk[1][tid]+pblk[2][tid]+pblk[3][tid];
  }
}

// ---------------- scan: offsets, tile map, aux loss ----------------
__global__ void __launch_bounds__(256)
scan_kernel(Ctrl* __restrict__ c, const float* __restrict__ Ppart, float* __restrict__ out){
  __shared__ float red[256];
  __shared__ float tot[8];
  int tid = threadIdx.x;
  for(int e=0;e<8;e++){
    float v=0.f;
    for(int i=tid;i<2048;i+=256) v += Ppart[i*8+e];
    red[tid]=v; __syncthreads();
    for(int s=128;s>0;s>>=1){ if(tid<s) red[tid]+=red[tid+s]; __syncthreads(); }
    if(tid==0) tot[e]=red[0];
    __syncthreads();
  }
  if(tid==0){
    int o=0, tc=0;
    float aux=0.f;
    for(int e=0;e<8;e++){
      c->offpad[e]=o;
      int nt = (c->cnt[e]+TM-1)/TM;
      for(int i=0;i<nt;i++) c->texp[tc++]=e;
      o += nt*TM;
      c->cursor[e]=0;
      aux += ((float)c->cnt[e]/(float)NTOK) * (tot[e]/(float)NTOK);
    }
    c->offpad[8]=o;
    c->ntiles=tc;
    out[(size_t)NTOK*D_MODEL] = 8.0f*0.01f*aux;   // aux_loss slot
  }
}

// ---------------- scatter tokens into per-expert entry lists ----------------
__global__ void __launch_bounds__(256)
scatter_kernel(const int* __restrict__ tok_e, const float* __restrict__ tok_s,
               Ctrl* __restrict__ c, int* __restrict__ etok, float* __restrict__ escl,
               int* __restrict__ pos){
  int t = blockIdx.x*256 + threadIdx.x;
  if(t >= NTOK) return;
  #pragma unroll
  for(int k=0;k<2;k++){
    int e = tok_e[2*t+k];
    int p = atomicAdd(&c->cursor[e],1);
    int i = c->offpad[e]+p;
    etok[i]=t; escl[i]=tok_s[2*t+k];
    pos[2*t+k]=i;
  }
}

// ---------------- phase A: G = silu(X W1^T) * (X V1^T) ----------------
// BM=256 x BF=128 (W & V), BK=32 -> LDS 64KB -> 2 blocks/CU. 8 waves 2Mx4N,
// wave = 128r x 32ffpair. Zigzag (0.375 reads/MFMA), strict dbuf, counted vmcnt(4).
__global__ void __launch_bounds__(512,2)
expA_kernel(const unsigned short* __restrict__ Xb, const unsigned short* __restrict__ W1b,
            const unsigned short* __restrict__ V1b, const int* __restrict__ etok,
            const Ctrl* __restrict__ c, unsigned short* __restrict__ G){
  __shared__ short8 As[2][1024];   // [buf][row*4 + chunk], 256 rows x 4 chunks
  __shared__ short8 Bs[2][1024];   // [buf][(W 0-127 | V 128-255)*4 + chunk]
  int bid = blockIdx.x;                  // 1152 = 8 XCD-chunks * 144
  int chunk = bid & 7;
  int w_in = bid >> 3;                   // 144 = 16 fb * 9 mtiles; fb-outer (L2 panel reuse)
  int fb = w_in / 9;
  int tile = chunk*9 + (w_in - fb*9);
  int fbase = fb * 128;
  if(tile >= c->ntiles) return;
  int e = c->texp[tile];
  int base = tile*TM;
  int tid = threadIdx.x;

  // staging: thread tid -> LDS slot tid (per 128-row gload unit): row r=tid>>2, chunk cc=tid&3
  int r = tid>>2, cc = tid&3;
  int swr = (r ^ (r>>2)) & 3;
  int cs = cc ^ swr;                     // inverse-swizzled source chunk
  int t0 = etok[base + r];
  int t1 = etok[base + 128 + r];
  const unsigned short* sA0 = Xb + (size_t)t0*D_MODEL + cs*8;
  const unsigned short* sA1 = Xb + (size_t)t1*D_MODEL + cs*8;
  const unsigned short* WE = W1b + (size_t)e*(D_FF*D_MODEL);
  const unsigned short* VE = V1b + (size_t)e*(D_FF*D_MODEL);
  const unsigned short* sB0 = WE + (size_t)(fbase+r)*D_MODEL + cs*8;
  const unsigned short* sB1 = VE + (size_t)(fbase+r)*D_MODEL + cs*8;
  int w64 = tid & ~63;

  int lane = tid&63, lrow = lane&15, lk = lane>>4;
  int wid = tid>>6, wr = wid>>2, wc = wid&3;
  int sw = (lrow ^ (lrow>>2)) & 3;       // uniform swizzle for ALL reads (rows mod 4 = lrow mod 4)
  int ch = lk ^ sw;                      // the single K-chunk this lane reads

  f32x4 hacc[8][2], vacc[8][2];
  #pragma unroll
  for(int mi=0;mi<8;mi++)
    #pragma unroll
    for(int nj=0;nj<2;nj++){
      hacc[mi][nj]=(f32x4){0.f,0.f,0.f,0.f};
      vacc[mi][nj]=(f32x4){0.f,0.f,0.f,0.f};
    }

  auto STAGE = [&](int b, int kt){       // 4 gloads = 32KB (A 16KB + B 16KB)
    size_t o = (size_t)kt*32;
    gload16(sA0+o, &As[b][w64]);         // A rows 0-127
    gload16(sA1+o, &As[b][512+w64]);     // A rows 128-255
    gload16(sB0+o, &Bs[b][w64]);         // W rows 0-127
    gload16(sB1+o, &Bs[b][512+w64]);     // V rows 0-127 (slots 512+)
  };

  STAGE(0,0);                            // 4 in flight

  #pragma unroll 2
  for(int kt=0; kt<16; kt++){
    const int cur = kt&1, nxt = cur^1;
    BAR;                                 // WAR: prior iter's reads of buf[nxt] done (all waves)
    if(kt<15) STAGE(nxt, kt+1);
    if(kt<15){ VM(4); } else { VM(0); }  // counted: kt's 4 loads retired; kt+1's stay in flight
    BAR;                                 // cross-wave: all waves' staged data visible
    short8 alo[4], ahi[4], bw[2], bv[2];
    __builtin_amdgcn_s_setprio(1);
    // ph1: A-lo + W -> hacc lo
    #pragma unroll
    for(int j=0;j<4;j++) alo[j] = As[cur][(wr*128 + j*16 + lrow)*4 + ch];
    #pragma unroll
    for(int nj=0;nj<2;nj++) bw[nj] = Bs[cur][(wc*32 + nj*16 + lrow)*4 + ch];
    #pragma unroll
    for(int j=0;j<4;j++)
      #pragma unroll
      for(int nj=0;nj<2;nj++)
        hacc[j][nj] = __builtin_amdgcn_mfma_f32_16x16x32_bf16(alo[j], bw[nj], hacc[j][nj],0,0,0);
    // ph2: V -> vacc lo (A-lo reused)
    #pragma unroll
    for(int nj=0;nj<2;nj++) bv[nj] = Bs[cur][512 + (wc*32 + nj*16 + lrow)*4 + ch];
    #pragma unroll
    for(int j=0;j<4;j++)
      #pragma unroll
      for(int nj=0;nj<2;nj++)
        vacc[j][nj] = __builtin_amdgcn_mfma_f32_16x16x32_bf16(alo[j], bv[nj], vacc[j][nj],0,0,0);
    // ph3: A-hi -> vacc hi (V reused)
    #pragma unroll
    for(int j=0;j<4;j++) ahi[j] = As[cur][(wr*128 + 64 + j*16 + lrow)*4 + ch];
    #pragma unroll
    for(int j=0;j<4;j++)
      #pragma unroll
      for(int nj=0;nj<2;nj++)
        vacc[4+j][nj] = __builtin_amdgcn_mfma_f32_16x16x32_bf16(ahi[j], bv[nj], vacc[4+j][nj],0,0,0);
    // ph4: hacc hi (A-hi, W reused; no reads)
    #pragma unroll
    for(int j=0;j<4;j++)
      #pragma unroll
      for(int nj=0;nj<2;nj++)
        hacc[4+j][nj] = __builtin_amdgcn_mfma_f32_16x16x32_bf16(ahi[j], bw[nj], hacc[4+j][nj],0,0,0);
    __builtin_amdgcn_s_setprio(0);
  }

  #pragma unroll
  for(int mi=0;mi<8;mi++){
    int m = base + wr*128 + mi*16 + lk*4;
    #pragma unroll
    for(int nj=0;nj<2;nj++){
      int f = fbase + wc*32 + nj*16 + lrow;
      #pragma unroll
      for(int rr=0;rr<4;rr++){
        float h = hacc[mi][nj][rr], vv = vacc[mi][nj][rr];
        float g = (h/(1.0f+__expf(-h)))*vv;
        G[(size_t)(m+rr)*D_FF + f] = f2bf(g);
      }
    }
  }
}

// ---------------- phase B: Ye = G W2^T (per-entry rows, no atomics) ----------------
// BM=128 x BN=128, K=2048 (32 K-tiles, BK=64). 256 thr / 4 waves (2x2), wave 64x64.
// 64KB LDS -> 2 blocks/CU. Counted vmcnt(8) pattern.
__global__ void __launch_bounds__(256,2)
expB_kernel(const unsigned short* __restrict__ G, const unsigned short* __restrict__ W2b,
            const Ctrl* __restrict__ c, unsigned short* __restrict__ Ye){
  __shared__ short8 As2[2][1024];  // 128 rows x 8 chunks
  __shared__ short8 Bs2[2][1024];  // 128 rows x 8 chunks
  int bid = blockIdx.x;            // 576 = 8 * (4 nb * 18 mtiles)
  int chunk = bid & 7;
  int w = bid >> 3;                // nb-outer, mtile-inner
  int nb = w / 18;
  int mtile = chunk*18 + (w - nb*18);   // 0..143
  if(mtile >= (c->offpad[8] >> 7)) return;
  int e = c->texp[mtile>>1];
  int base = mtile*128;
  int nbase = nb*128;
  int tid = threadIdx.x;

  int r0 = tid>>3, cc = tid&7;
  int cs = cc ^ (r0&7);
  const unsigned short* sA0 = G + (size_t)(base + r0     )*D_FF + cs*8;
  const unsigned short* sA1 = G + (size_t)(base + r0 + 32)*D_FF + cs*8;
  const unsigned short* sA2 = G + (size_t)(base + r0 + 64)*D_FF + cs*8;
  const unsigned short* sA3 = G + (size_t)(base + r0 + 96)*D_FF + cs*8;
  const unsigned short* W2E = W2b + (size_t)e*(D_MODEL*D_FF);
  const unsigned short* sB0 = W2E + (size_t)(nbase + r0     )*D_FF + cs*8;
  const unsigned short* sB1 = W2E + (size_t)(nbase + r0 + 32)*D_FF + cs*8;
  const unsigned short* sB2 = W2E + (size_t)(nbase + r0 + 64)*D_FF + cs*8;
  const unsigned short* sB3 = W2E + (size_t)(nbase + r0 + 96)*D_FF + cs*8;
  int w64 = tid & ~63;

  int lane = tid&63, lrow = lane&15, lk = lane>>4;
  int wv = tid>>6, wm = wv>>1, wn = wv&1;

  f32x4 acc[4][4];
  #pragma unroll
  for(int mi=0;mi<4;mi++)
    #pragma unroll
    for(int nj=0;nj<4;nj++) acc[mi][nj]=(f32x4){0.f,0.f,0.f,0.f};

  auto STAGE = [&](int b, int t){
    size_t o = (size_t)t*64;
    gload16(sA0+o, &As2[b][w64      ]);
    gload16(sA1+o, &As2[b][w64 + 256]);
    gload16(sA2+o, &As2[b][w64 + 512]);
    gload16(sA3+o, &As2[b][w64 + 768]);
    gload16(sB0+o, &Bs2[b][w64      ]);
    gload16(sB1+o, &Bs2[b][w64 + 256]);
    gload16(sB2+o, &Bs2[b][w64 + 512]);
    gload16(sB3+o, &Bs2[b][w64 + 768]);
  };

  STAGE(0,0);

  #pragma unroll 2
  for(int t=0;t<32;t++){
    const int cur = t&1, nxt = cur^1;
    BAR;                                 // WAR across waves
    if(t<31) STAGE(nxt, t+1);
    if(t<31){ VM(8); } else { VM(0); }   // counted retire of tile t's 8 loads
    BAR;                                 // cross-wave visibility
    short8 a[4][2], b[4][2];
    #pragma unroll
    for(int ks=0;ks<2;ks++){
      #pragma unroll
      for(int mi=0;mi<4;mi++){
        int arow = wm*64 + mi*16 + lrow;
        a[mi][ks] = As2[cur][arow*8 + ((ks*4+lk) ^ (arow&7))];
      }
      #pragma unroll
      for(int nj=0;nj<4;nj++){
        int brow = wn*64 + nj*16 + lrow;
        b[nj][ks] = Bs2[cur][brow*8 + ((ks*4+lk) ^ (brow&7))];
      }
    }
    __builtin_amdgcn_s_setprio(1);
    #pragma unroll
    for(int ks=0;ks<2;ks++)
      #pragma unroll
      for(int mi=0;mi<4;mi++)
        #pragma unroll
        for(int nj=0;nj<4;nj++)
          acc[mi][nj] = __builtin_amdgcn_mfma_f32_16x16x32_bf16(a[mi][ks], b[nj][ks], acc[mi][nj],0,0,0);
    __builtin_amdgcn_s_setprio(0);
  }

  #pragma unroll
  for(int mi=0;mi<4;mi++){
    #pragma unroll
    for(int r=0;r<4;r++){
      int m = base + wm*64 + mi*16 + lk*4 + r;
      #pragma unroll
      for(int nj=0;nj<4;nj++){
        int n = nbase + wn*64 + nj*16 + lrow;
        Ye[(size_t)m*D_MODEL + n] = f2bf(acc[mi][nj][r]);
      }
    }
  }
}

// ---------------- combine: out[t] = s0*Ye[p0] + s1*Ye[p1] ----------------
__global__ void __launch_bounds__(256)
combine_kernel(const unsigned short* __restrict__ Ye, const int* __restrict__ pos,
               const float* __restrict__ tok_s, float* __restrict__ out){
  int wave = threadIdx.x>>6, lane = threadIdx.x&63;
  int t = blockIdx.x*4 + wave;
  int p0 = pos[2*t], p1 = pos[2*t+1];
  float s0 = tok_s[2*t], s1 = tok_s[2*t+1];
  short8 y0 = *(const short8*)(Ye + (size_t)p0*D_MODEL + lane*8);
  short8 y1 = *(const short8*)(Ye + (size_t)p1*D_MODEL + lane*8);
  float* o = out + (size_t)t*D_MODEL + lane*8;
  float v[8];
  #pragma unroll
  for(int i=0;i<8;i++)
    v[i] = s0*bf2f((unsigned short)y0[i]) + s1*bf2f((unsigned short)y1[i]);
  float4 lo = {v[0],v[1],v[2],v[3]};
  float4 hi = {v[4],v[5],v[6],v[7]};
  *(float4*)o = lo;
  *(float4*)(o+4) = hi;
}

extern "C" void kernel_launch(void* const* d_in, const int* in_sizes, int n_in,
                              void* d_out, int out_size, void* d_ws, size_t ws_size,
                              hipStream_t stream) {
  (void)in_sizes; (void)n_in; (void)out_size;
  const float* x  = (const float*)d_in[0];
  const float* gw = (const float*)d_in[1];
  const float* W1 = (const float*)d_in[2];
  const float* V1 = (const float*)d_in[3];
  const float* W2 = (const float*)d_in[4];
  float* out = (float*)d_out;

  const size_t WSZ = (size_t)N_EXP*D_FF*D_MODEL;     // 8.39M elems per weight
  const size_t XSZ = (size_t)NTOK*D_MODEL;           // 4.19M
  char* ws = (char*)d_ws;
  size_t off = 0;
  unsigned short* W1b = (unsigned short*)(ws+off); off += WSZ*2;
  unsigned short* V1b = (unsigned short*)(ws+off); size_t v1_off = off; off += WSZ*2;
  unsigned short* Xb  = (unsigned short*)(ws+off); off += XSZ*2;
  unsigned short* G   = (unsigned short*)(ws+off); off += (size_t)NEPAD*D_FF*2;
  int*   etok  = (int*)(ws+off);   size_t entry_off = off; off += (size_t)NEPAD*4;
  float* escl  = (float*)(ws+off); off += (size_t)NEPAD*4;
  size_t entry_bytes = off - entry_off;
  int*   pos   = (int*)(ws+off);   off += (size_t)NTOK*2*4;
  int*   tok_e = (int*)(ws+off);   off += (size_t)NTOK*2*4;
  float* tok_s = (float*)(ws+off); off += (size_t)NTOK*2*4;
  float* Ppart = (float*)(ws+off); off += (size_t)2048*8*4;
  Ctrl*  ctrl  = (Ctrl*)(ws+off);  off += sizeof(Ctrl);
  // Ye (single): 18432*512*2 = 18.87MB, fits V1b(16.78)+Xb(8.39)=25.17MB dead region
  unsigned short* Ye  = (unsigned short*)(ws+v1_off);
  if(ws_size < off) return;

  // optional dedicated W2 buffer (lets W2 cvt run before expA, no serial bubble)
  unsigned short* W2d = (unsigned short*)(ws+off);
  bool hoistW2 = (ws_size >= off + WSZ*2);
  unsigned short* W2b = hoistW2 ? W2d : W1b;

  hipMemsetAsync(ws+entry_off, 0, entry_bytes, stream);
  hipMemsetAsync(ctrl, 0, sizeof(Ctrl), stream);

  cvt3_kernel<<<dim3(4096, hoistW2 ? 3 : 2), 256, 0, stream>>>(W1, V1, W2, W1b, V1b, W2d);

  gate_kernel<<<NTOK/4, 256, 0, stream>>>(x, gw, tok_e, tok_s, ctrl, Ppart, Xb);
  scan_kernel<<<1, 256, 0, stream>>>(ctrl, Ppart, out);
  scatter_kernel<<<NTOK/256, 256, 0, stream>>>(tok_e, tok_s, ctrl, etok, escl, pos);

  expA_kernel<<<1152, 512, 0, stream>>>(Xb, W1b, V1b, etok, ctrl, G);
  if(!hoistW2)
    cvt_kernel<<<(int)WSZ/(256*8), 256, 0, stream>>>(W2, W1b, (int)WSZ);  // into W1b region
  expB_kernel<<<576, 256, 0, stream>>>(G, W2b, ctrl, Ye);
  combine_kernel<<<NTOK/4, 256, 0, stream>>>(Ye, pos, tok_s, out);
}

// Round 9
// 316.182 us; speedup vs baseline: 1.1312x; 1.1312x over previous
//
#include <hip/hip_runtime.h>
#include <hip/hip_bf16.h>
#include <stdint.h>

#define D_MODEL 512
#define N_EXP 8
#define D_FF 2048
#define NTOK 8192
#define TM 256
#define MAX_TILES 72                 /* ceil(16384/256) + 8 */
#define NEPAD (MAX_TILES*TM)         /* 18432 */
#define BK 64

typedef __attribute__((ext_vector_type(8))) short short8;
typedef __attribute__((ext_vector_type(4))) float f32x4;

struct Ctrl {
  int cnt[8];
  int cursor[8];
  int offpad[16];
  int ntiles;
  int pad[3];
  int texp[MAX_TILES];
};

__device__ __forceinline__ unsigned short f2bf(float f){
  unsigned u = __float_as_uint(f);
  u += 0x7FFFu + ((u>>16)&1u);          // RNE
  return (unsigned short)(u>>16);
}
__device__ __forceinline__ float bf2f(unsigned short v){
  return __uint_as_float(((unsigned)v)<<16);
}

__device__ __forceinline__ short8 pack8(float4 a, float4 b){
  short8 o;
  o[0]=(short)f2bf(a.x); o[1]=(short)f2bf(a.y); o[2]=(short)f2bf(a.z); o[3]=(short)f2bf(a.w);
  o[4]=(short)f2bf(b.x); o[5]=(short)f2bf(b.y); o[6]=(short)f2bf(b.z); o[7]=(short)f2bf(b.w);
  return o;
}

__device__ __forceinline__ void gload16(const void* g, void* l){
  __builtin_amdgcn_global_load_lds((const __attribute__((address_space(1))) unsigned int*)g,
                                   (__attribute__((address_space(3))) unsigned int*)l, 16, 0, 0);
}

#define SBAR0 __builtin_amdgcn_sched_barrier(0)
#define BAR   do{ SBAR0; __builtin_amdgcn_s_barrier(); SBAR0; }while(0)
#define LGKM0 do{ asm volatile("s_waitcnt lgkmcnt(0)" ::: "memory"); SBAR0; }while(0)
#define VM(N) do{ asm volatile("s_waitcnt vmcnt(" #N ")" ::: "memory"); SBAR0; }while(0)

// ---------------- prep: gate (blocks 0..2047) + weight f32->bf16 (rest) ----------------
__global__ void __launch_bounds__(256)
prep_kernel(const float* __restrict__ x, const float* __restrict__ gw,
            const float* __restrict__ W1, const float* __restrict__ V1, const float* __restrict__ W2,
            unsigned short* __restrict__ W1b, unsigned short* __restrict__ V1b, unsigned short* __restrict__ W2d,
            int* __restrict__ tok_e, float* __restrict__ tok_s,
            Ctrl* __restrict__ c, float* __restrict__ Pbins,
            unsigned short* __restrict__ Xb){
  __shared__ float gws[N_EXP*D_MODEL];
  __shared__ float pblk[4][8];
  __shared__ int cblk[8];
  int bid = blockIdx.x;
  int tid = threadIdx.x;
  if(bid >= 2048){
    // ---- weight conversion part ----
    int j = bid - 2048;
    const float* src = (j<4096) ? W1 : (j<8192 ? V1 : W2);
    unsigned short* dst = (j<4096) ? W1b : (j<8192 ? V1b : W2d);
    int i = (j & 4095)*2048 + tid*8;
    float4 a = *(const float4*)(src+i);
    float4 b = *(const float4*)(src+i+4);
    *(short8*)(dst+i) = pack8(a,b);
    return;
  }
  // ---- gating part (+ x->bf16) ----
  for(int i=tid; i<N_EXP*D_MODEL; i+=256) gws[i]=gw[i];
  if(tid<8) cblk[tid]=0;
  __syncthreads();
  int wave = tid>>6, lane = tid&63;
  int t = bid*4 + wave;
  const float* xr = x + (size_t)t*D_MODEL + lane*8;
  float4 xa = *(const float4*)xr;
  float4 xb = *(const float4*)(xr+4);
  *(short8*)(Xb + (size_t)t*D_MODEL + lane*8) = pack8(xa,xb);
  float le[8];
  #pragma unroll
  for(int e=0;e<8;e++){
    const float* g = gws + e*D_MODEL + lane*8;
    float4 ga = *(const float4*)g;
    float4 gb = *(const float4*)(g+4);
    le[e] = xa.x*ga.x + xa.y*ga.y + xa.z*ga.z + xa.w*ga.w
          + xb.x*gb.x + xb.y*gb.y + xb.z*gb.z + xb.w*gb.w;
  }
  #pragma unroll
  for(int e=0;e<8;e++){
    float v = le[e];
    #pragma unroll
    for(int off=1; off<64; off<<=1) v += __shfl_xor(v, off);
    le[e]=v;
  }
  float mx = le[0];
  #pragma unroll
  for(int e=1;e<8;e++) mx = fmaxf(mx, le[e]);
  float p[8], s=0.f;
  #pragma unroll
  for(int e=0;e<8;e++){ p[e]=__expf(le[e]-mx); s+=p[e]; }
  float inv = 1.0f/s;
  #pragma unroll
  for(int e=0;e<8;e++) p[e]*=inv;
  int e0=0; float s0=p[0];
  #pragma unroll
  for(int e=1;e<8;e++) if(p[e]>s0){e0=e;s0=p[e];}
  int e1=-1; float s1=-1.f;
  #pragma unroll
  for(int e=0;e<8;e++) if(e!=e0 && p[e]>s1){e1=e;s1=p[e];}
  if(lane==0){
    tok_e[2*t]=e0; tok_e[2*t+1]=e1;
    tok_s[2*t]=s0; tok_s[2*t+1]=s1;
    atomicAdd(&cblk[e0],1); atomicAdd(&cblk[e1],1);
    #pragma unroll
    for(int e=0;e<8;e++) pblk[wave][e]=p[e];
  }
  __syncthreads();
  if(tid<8){
    atomicAdd(&c->cnt[tid], cblk[tid]);
    atomicAdd(&Pbins[(bid&63)*8 + tid],
              pblk[0][tid]+pblk[1][tid]+pblk[2][tid]+pblk[3][tid]);
  }
}

__global__ void __launch_bounds__(256)
cvt_kernel(const float* __restrict__ src, unsigned short* __restrict__ dst, int n){
  int i = (blockIdx.x*256 + threadIdx.x)*8;
  if(i >= n) return;
  float4 a = *(const float4*)(src+i);
  float4 b = *(const float4*)(src+i+4);
  *(short8*)(dst+i) = pack8(a,b);
}

// ---------------- scan: offsets, tile map, aux loss (fast Pbins reduce) ----------------
__global__ void __launch_bounds__(256)
scan_kernel(Ctrl* __restrict__ c, const float* __restrict__ Pbins, float* __restrict__ out){
  __shared__ float pred[4][8];
  int tid = threadIdx.x;
  float v = Pbins[tid] + Pbins[tid+256];    // 512 bins = 64 x 8 experts
  v += __shfl_xor(v, 8);
  v += __shfl_xor(v, 16);
  v += __shfl_xor(v, 32);
  if((tid&63)<8) pred[tid>>6][tid&7] = v;   // lane l<8 holds expert l's wave-sum
  __syncthreads();
  if(tid==0){
    int o=0, tc=0;
    float aux=0.f;
    for(int e=0;e<8;e++){
      float tot = pred[0][e]+pred[1][e]+pred[2][e]+pred[3][e];
      c->offpad[e]=o;
      int nt = (c->cnt[e]+TM-1)/TM;
      for(int i=0;i<nt;i++) c->texp[tc++]=e;
      o += nt*TM;
      c->cursor[e]=0;
      aux += ((float)c->cnt[e]/(float)NTOK) * (tot/(float)NTOK);
    }
    c->offpad[8]=o;
    c->ntiles=tc;
    out[(size_t)NTOK*D_MODEL] = 8.0f*0.01f*aux;   // aux_loss slot
  }
}

// ---------------- scatter tokens into per-expert entry lists ----------------
__global__ void __launch_bounds__(256)
scatter_kernel(const int* __restrict__ tok_e, const float* __restrict__ tok_s,
               Ctrl* __restrict__ c, int* __restrict__ etok, float* __restrict__ escl,
               int* __restrict__ pos){
  int t = blockIdx.x*256 + threadIdx.x;
  if(t >= NTOK) return;
  #pragma unroll
  for(int k=0;k<2;k++){
    int e = tok_e[2*t+k];
    int p = atomicAdd(&c->cursor[e],1);
    int i = c->offpad[e]+p;
    etok[i]=t; escl[i]=tok_s[2*t+k];
    pos[2*t+k]=i;
  }
}

// ---------------- phase A: G = silu(X W1^T) * (X V1^T) ----------------
// tile 256 x (128 W + 128 V). 8 waves 2Mx4N, wave = 128r x 64effc.
// 4-phase zigzag/K-tile: ph1 Alo*W, ph2 Alo*V, ph3 Ahi*V, ph4 Ahi*W.
// stages: ph1 A1(k+1)->nxt, ph2 W(k+2)->cur, ph3 V(k+2)->cur, ph4 A0(k+2)->cur, vmcnt(6).
__global__ void __launch_bounds__(512,2)
expA_kernel(const unsigned short* __restrict__ Xb, const unsigned short* __restrict__ W1b,
            const unsigned short* __restrict__ V1b, const int* __restrict__ etok,
            const Ctrl* __restrict__ c, unsigned short* __restrict__ G){
  __shared__ short8 As[2][2048];   // [par][row*8 + swz chunk], rows 0-255
  __shared__ short8 Bs[2][2048];   // [par][W rows 0-127 | V rows 0-127]
  int bid = blockIdx.x;                  // 1152 = 8 XCD-chunks * 144
  int chunk = bid & 7;
  int w_in = bid >> 3;                   // fb-outer, tile-inner (B-panel L2 reuse)
  int fb = w_in / 9;
  int tile = chunk*9 + (w_in - fb*9);
  int fbase = fb * 128;
  if(tile >= c->ntiles) return;
  int e = c->texp[tile];
  int base = tile*TM;
  int tid = threadIdx.x;

  int r0 = tid>>3;
  int cs = (tid&7) ^ (r0&7);             // inverse-swizzled global source chunk
  int t0 = etok[base + r0];
  int t1 = etok[base + 64 + r0];
  int t2 = etok[base + 128 + r0];
  int t3 = etok[base + 192 + r0];
  const unsigned short* sA0 = Xb + (size_t)t0*D_MODEL + cs*8;
  const unsigned short* sA1 = Xb + (size_t)t1*D_MODEL + cs*8;
  const unsigned short* sA2 = Xb + (size_t)t2*D_MODEL + cs*8;
  const unsigned short* sA3 = Xb + (size_t)t3*D_MODEL + cs*8;
  const unsigned short* WE = W1b + (size_t)e*(D_FF*D_MODEL);
  const unsigned short* VE = V1b + (size_t)e*(D_FF*D_MODEL);
  const unsigned short* sB0 = WE + (size_t)(fbase+r0)*D_MODEL + cs*8;
  const unsigned short* sB1 = WE + (size_t)(fbase+64+r0)*D_MODEL + cs*8;
  const unsigned short* sB2 = VE + (size_t)(fbase+r0)*D_MODEL + cs*8;
  const unsigned short* sB3 = VE + (size_t)(fbase+64+r0)*D_MODEL + cs*8;
  int w64 = tid & ~63;

  int lane = tid&63, lrow = lane&15, lk = lane>>4;
  int wid = tid>>6, wr = wid>>2, wc = wid&3;
  int sw = lrow&7;
  int ch0 = lk ^ sw;
  int ch1 = (4+lk) ^ sw;

  f32x4 hacc[8][2], vacc[8][2];
  #pragma unroll
  for(int mi=0;mi<8;mi++)
    #pragma unroll
    for(int nj=0;nj<2;nj++){
      hacc[mi][nj]=(f32x4){0.f,0.f,0.f,0.f};
      vacc[mi][nj]=(f32x4){0.f,0.f,0.f,0.f};
    }

  auto ST_A0 = [&](int b, int kt){ size_t o=(size_t)kt*BK; gload16(sA0+o, &As[b][w64]);      gload16(sA1+o, &As[b][512+w64]); };
  auto ST_A1 = [&](int b, int kt){ size_t o=(size_t)kt*BK; gload16(sA2+o, &As[b][1024+w64]); gload16(sA3+o, &As[b][1536+w64]); };
  auto ST_W  = [&](int b, int kt){ size_t o=(size_t)kt*BK; gload16(sB0+o, &Bs[b][w64]);      gload16(sB1+o, &Bs[b][512+w64]); };
  auto ST_V  = [&](int b, int kt){ size_t o=(size_t)kt*BK; gload16(sB2+o, &Bs[b][1024+w64]); gload16(sB3+o, &Bs[b][1536+w64]); };

  // prologue: tile0 full + W,V,A0 of tile1 (14 loads); vmcnt(6) completes tile0.
  ST_A0(0,0); ST_A1(0,0); ST_W(0,0); ST_V(0,0);
  ST_W(1,1); ST_V(1,1); ST_A0(1,1);
  VM(6);
  BAR;

  short8 alo[4][2], ahi[4][2], bw[2][2], bv[2][2];

  #pragma unroll
  for(int k=0;k<8;k++){
    const int cur = k&1, nxt = cur^1;
    // ---- ph1: read A-lo + W ; stage A1(k+1) ; MFMA hacc lo ----
    #pragma unroll
    for(int j=0;j<4;j++){
      int s = (wr*128 + j*16 + lrow)*8;
      alo[j][0] = As[cur][s + ch0];
      alo[j][1] = As[cur][s + ch1];
    }
    #pragma unroll
    for(int nj=0;nj<2;nj++){
      int s = (wc*32 + nj*16 + lrow)*8;
      bw[nj][0] = Bs[cur][s + ch0];
      bw[nj][1] = Bs[cur][s + ch1];
    }
    if(k<7) ST_A1(nxt, k+1);
    BAR; LGKM0;
    __builtin_amdgcn_s_setprio(1);
    #pragma unroll
    for(int j=0;j<4;j++)
      #pragma unroll
      for(int nj=0;nj<2;nj++){
        hacc[j][nj] = __builtin_amdgcn_mfma_f32_16x16x32_bf16(alo[j][0], bw[nj][0], hacc[j][nj],0,0,0);
        hacc[j][nj] = __builtin_amdgcn_mfma_f32_16x16x32_bf16(alo[j][1], bw[nj][1], hacc[j][nj],0,0,0);
      }
    __builtin_amdgcn_s_setprio(0);
    BAR;
    // ---- ph2: read V ; stage W(k+2) ; MFMA vacc lo ----
    #pragma unroll
    for(int nj=0;nj<2;nj++){
      int s = 1024 + (wc*32 + nj*16 + lrow)*8;
      bv[nj][0] = Bs[cur][s + ch0];
      bv[nj][1] = Bs[cur][s + ch1];
    }
    if(k<6) ST_W(cur, k+2);
    BAR; LGKM0;
    __builtin_amdgcn_s_setprio(1);
    #pragma unroll
    for(int j=0;j<4;j++)
      #pragma unroll
      for(int nj=0;nj<2;nj++){
        vacc[j][nj] = __builtin_amdgcn_mfma_f32_16x16x32_bf16(alo[j][0], bv[nj][0], vacc[j][nj],0,0,0);
        vacc[j][nj] = __builtin_amdgcn_mfma_f32_16x16x32_bf16(alo[j][1], bv[nj][1], vacc[j][nj],0,0,0);
      }
    __builtin_amdgcn_s_setprio(0);
    BAR;
    // ---- ph3: read A-hi ; stage V(k+2) ; MFMA vacc hi ----
    #pragma unroll
    for(int j=0;j<4;j++){
      int s = (wr*128 + 64 + j*16 + lrow)*8;
      ahi[j][0] = As[cur][s + ch0];
      ahi[j][1] = As[cur][s + ch1];
    }
    if(k<6) ST_V(cur, k+2);
    BAR; LGKM0;
    __builtin_amdgcn_s_setprio(1);
    #pragma unroll
    for(int j=0;j<4;j++)
      #pragma unroll
      for(int nj=0;nj<2;nj++){
        vacc[4+j][nj] = __builtin_amdgcn_mfma_f32_16x16x32_bf16(ahi[j][0], bv[nj][0], vacc[4+j][nj],0,0,0);
        vacc[4+j][nj] = __builtin_amdgcn_mfma_f32_16x16x32_bf16(ahi[j][1], bv[nj][1], vacc[4+j][nj],0,0,0);
      }
    __builtin_amdgcn_s_setprio(0);
    BAR;
    // ---- ph4: no reads ; stage A0(k+2) ; vmcnt gate ; MFMA hacc hi ----
    if(k<6) ST_A0(cur, k+2);
    if(k<6){ VM(6); } else { VM(0); }
    BAR;
    __builtin_amdgcn_s_setprio(1);
    #pragma unroll
    for(int j=0;j<4;j++)
      #pragma unroll
      for(int nj=0;nj<2;nj++){
        hacc[4+j][nj] = __builtin_amdgcn_mfma_f32_16x16x32_bf16(ahi[j][0], bw[nj][0], hacc[4+j][nj],0,0,0);
        hacc[4+j][nj] = __builtin_amdgcn_mfma_f32_16x16x32_bf16(ahi[j][1], bw[nj][1], hacc[4+j][nj],0,0,0);
      }
    __builtin_amdgcn_s_setprio(0);
    BAR;
  }

  #pragma unroll
  for(int mi=0;mi<8;mi++){
    int m = base + wr*128 + mi*16 + lk*4;
    #pragma unroll
    for(int nj=0;nj<2;nj++){
      int f = fbase + wc*32 + nj*16 + lrow;
      #pragma unroll
      for(int r=0;r<4;r++){
        float h = hacc[mi][nj][r], vv = vacc[mi][nj][r];
        float g = (h/(1.0f+__expf(-h)))*vv;
        G[(size_t)(m+r)*D_FF + f] = f2bf(g);
      }
    }
  }
}

// ---------------- phase B: Ye = G W2^T (per-entry rows, no atomics, no K-split) ----------------
// tile 256 entries x 256 n-cols (nb 2), K=2048 -> 32 K-tiles. Zigzag template.
// stages: ph1 A0(k+1)->nxt, ph2 A1(k+1)->nxt, ph3 B0(k+2)->cur, ph4 B1(k+2)->cur; vmcnt(4).
__global__ void __launch_bounds__(512,2)
expB_kernel(const unsigned short* __restrict__ G, const unsigned short* __restrict__ W2b,
            const Ctrl* __restrict__ c, unsigned short* __restrict__ Ye){
  __shared__ short8 As2[2][2048];  // 256 rows x 8 chunks
  __shared__ short8 Bs2[2][2048];  // 256 rows x 8 chunks
  int bid = blockIdx.x;                 // 144 = 8*18
  int w = (bid & 7)*18 + (bid >> 3);    // XCD-chunked bijective swizzle
  int tile = w >> 1;
  int nb = w & 1;
  if(tile >= c->ntiles) return;
  int e = c->texp[tile];
  int base = tile*TM;
  int nbase = nb*256;
  int tid = threadIdx.x;

  int r0 = tid>>3;
  int cs = (tid&7) ^ (r0&7);
  const unsigned short* sA0 = G + (size_t)(base+r0)*D_FF + cs*8;
  const unsigned short* sA1 = G + (size_t)(base+64+r0)*D_FF + cs*8;
  const unsigned short* sA2 = G + (size_t)(base+128+r0)*D_FF + cs*8;
  const unsigned short* sA3 = G + (size_t)(base+192+r0)*D_FF + cs*8;
  const unsigned short* W2E = W2b + (size_t)e*(D_MODEL*D_FF);
  const unsigned short* sB0 = W2E + (size_t)(nbase+r0)*D_FF + cs*8;
  const unsigned short* sB1 = W2E + (size_t)(nbase+64+r0)*D_FF + cs*8;
  const unsigned short* sB2 = W2E + (size_t)(nbase+128+r0)*D_FF + cs*8;
  const unsigned short* sB3 = W2E + (size_t)(nbase+192+r0)*D_FF + cs*8;
  int w64 = tid & ~63;

  int lane = tid&63, lrow = lane&15, lk = lane>>4;
  int wid = tid>>6, wr = wid>>2, wc = wid&3;
  int sw = lrow&7;
  int ch0 = lk ^ sw;
  int ch1 = (4+lk) ^ sw;

  f32x4 acc[8][4];
  #pragma unroll
  for(int mi=0;mi<8;mi++)
    #pragma unroll
    for(int nj=0;nj<4;nj++) acc[mi][nj]=(f32x4){0.f,0.f,0.f,0.f};

  auto ST_A0 = [&](int b, int kt){ size_t o=(size_t)kt*BK; gload16(sA0+o, &As2[b][w64]);      gload16(sA1+o, &As2[b][512+w64]); };
  auto ST_A1 = [&](int b, int kt){ size_t o=(size_t)kt*BK; gload16(sA2+o, &As2[b][1024+w64]); gload16(sA3+o, &As2[b][1536+w64]); };
  auto ST_B0 = [&](int b, int kt){ size_t o=(size_t)kt*BK; gload16(sB0+o, &Bs2[b][w64]);      gload16(sB1+o, &Bs2[b][512+w64]); };
  auto ST_B1 = [&](int b, int kt){ size_t o=(size_t)kt*BK; gload16(sB2+o, &Bs2[b][1024+w64]); gload16(sB3+o, &Bs2[b][1536+w64]); };

  // prologue: tile0 full + B0,B1 of tile1 (12 loads); vmcnt(4) completes tile0.
  ST_B0(0,0); ST_B1(0,0); ST_A0(0,0); ST_A1(0,0);
  ST_B0(1,1); ST_B1(1,1);
  VM(4);
  BAR;

  short8 alo[4][2], ahi[4][2], bl[2][2], bh[2][2];

  #pragma unroll 2
  for(int k=0;k<32;k++){
    const int cur = k&1, nxt = cur^1;
    // ---- ph1: read A-lo + B-lo ; stage A0(k+1) ; MFMA lo x lo ----
    #pragma unroll
    for(int j=0;j<4;j++){
      int s = (wr*128 + j*16 + lrow)*8;
      alo[j][0] = As2[cur][s + ch0];
      alo[j][1] = As2[cur][s + ch1];
    }
    #pragma unroll
    for(int nj=0;nj<2;nj++){
      int s = (wc*64 + nj*16 + lrow)*8;
      bl[nj][0] = Bs2[cur][s + ch0];
      bl[nj][1] = Bs2[cur][s + ch1];
    }
    if(k<31) ST_A0(nxt, k+1);
    BAR; LGKM0;
    __builtin_amdgcn_s_setprio(1);
    #pragma unroll
    for(int j=0;j<4;j++)
      #pragma unroll
      for(int nj=0;nj<2;nj++){
        acc[j][nj] = __builtin_amdgcn_mfma_f32_16x16x32_bf16(alo[j][0], bl[nj][0], acc[j][nj],0,0,0);
        acc[j][nj] = __builtin_amdgcn_mfma_f32_16x16x32_bf16(alo[j][1], bl[nj][1], acc[j][nj],0,0,0);
      }
    __builtin_amdgcn_s_setprio(0);
    BAR;
    // ---- ph2: read B-hi ; stage A1(k+1) ; MFMA lo x hi ----
    #pragma unroll
    for(int nj=0;nj<2;nj++){
      int s = (wc*64 + 32 + nj*16 + lrow)*8;
      bh[nj][0] = Bs2[cur][s + ch0];
      bh[nj][1] = Bs2[cur][s + ch1];
    }
    if(k<31) ST_A1(nxt, k+1);
    BAR; LGKM0;
    __builtin_amdgcn_s_setprio(1);
    #pragma unroll
    for(int j=0;j<4;j++)
      #pragma unroll
      for(int nj=0;nj<2;nj++){
        acc[j][2+nj] = __builtin_amdgcn_mfma_f32_16x16x32_bf16(alo[j][0], bh[nj][0], acc[j][2+nj],0,0,0);
        acc[j][2+nj] = __builtin_amdgcn_mfma_f32_16x16x32_bf16(alo[j][1], bh[nj][1], acc[j][2+nj],0,0,0);
      }
    __builtin_amdgcn_s_setprio(0);
    BAR;
    // ---- ph3: read A-hi ; stage B0(k+2) ; MFMA hi x hi ----
    #pragma unroll
    for(int j=0;j<4;j++){
      int s = (wr*128 + 64 + j*16 + lrow)*8;
      ahi[j][0] = As2[cur][s + ch0];
      ahi[j][1] = As2[cur][s + ch1];
    }
    if(k<30) ST_B0(cur, k+2);
    BAR; LGKM0;
    __builtin_amdgcn_s_setprio(1);
    #pragma unroll
    for(int j=0;j<4;j++)
      #pragma unroll
      for(int nj=0;nj<2;nj++){
        acc[4+j][2+nj] = __builtin_amdgcn_mfma_f32_16x16x32_bf16(ahi[j][0], bh[nj][0], acc[4+j][2+nj],0,0,0);
        acc[4+j][2+nj] = __builtin_amdgcn_mfma_f32_16x16x32_bf16(ahi[j][1], bh[nj][1], acc[4+j][2+nj],0,0,0);
      }
    __builtin_amdgcn_s_setprio(0);
    BAR;
    // ---- ph4: no reads ; stage B1(k+2) ; vmcnt gate ; MFMA hi x lo ----
    if(k<30) ST_B1(cur, k+2);
    if(k<30){ VM(4); } else { VM(0); }
    BAR;
    __builtin_amdgcn_s_setprio(1);
    #pragma unroll
    for(int j=0;j<4;j++)
      #pragma unroll
      for(int nj=0;nj<2;nj++){
        acc[4+j][nj] = __builtin_amdgcn_mfma_f32_16x16x32_bf16(ahi[j][0], bl[nj][0], acc[4+j][nj],0,0,0);
        acc[4+j][nj] = __builtin_amdgcn_mfma_f32_16x16x32_bf16(ahi[j][1], bl[nj][1], acc[4+j][nj],0,0,0);
      }
    __builtin_amdgcn_s_setprio(0);
    BAR;
  }

  #pragma unroll
  for(int mi=0;mi<8;mi++){
    #pragma unroll
    for(int r=0;r<4;r++){
      int m = base + wr*128 + mi*16 + lk*4 + r;
      #pragma unroll
      for(int nj=0;nj<4;nj++){
        int n = nbase + wc*64 + nj*16 + lrow;
        Ye[(size_t)m*D_MODEL + n] = f2bf(acc[mi][nj][r]);
      }
    }
  }
}

// ---------------- combine: out[t] = s0*Ye[p0] + s1*Ye[p1] ----------------
__global__ void __launch_bounds__(256)
combine_kernel(const unsigned short* __restrict__ Ye, const int* __restrict__ pos,
               const float* __restrict__ tok_s, float* __restrict__ out){
  int wave = threadIdx.x>>6, lane = threadIdx.x&63;
  int t = blockIdx.x*4 + wave;
  int p0 = pos[2*t], p1 = pos[2*t+1];
  float s0 = tok_s[2*t], s1 = tok_s[2*t+1];
  short8 y0 = *(const short8*)(Ye + (size_t)p0*D_MODEL + lane*8);
  short8 y1 = *(const short8*)(Ye + (size_t)p1*D_MODEL + lane*8);
  float* o = out + (size_t)t*D_MODEL + lane*8;
  float v[8];
  #pragma unroll
  for(int i=0;i<8;i++)
    v[i] = s0*bf2f((unsigned short)y0[i]) + s1*bf2f((unsigned short)y1[i]);
  float4 lo = {v[0],v[1],v[2],v[3]};
  float4 hi = {v[4],v[5],v[6],v[7]};
  *(float4*)o = lo;
  *(float4*)(o+4) = hi;
}

extern "C" void kernel_launch(void* const* d_in, const int* in_sizes, int n_in,
                              void* d_out, int out_size, void* d_ws, size_t ws_size,
                              hipStream_t stream) {
  (void)in_sizes; (void)n_in; (void)out_size;
  const float* x  = (const float*)d_in[0];
  const float* gw = (const float*)d_in[1];
  const float* W1 = (const float*)d_in[2];
  const float* V1 = (const float*)d_in[3];
  const float* W2 = (const float*)d_in[4];
  float* out = (float*)d_out;

  const size_t WSZ = (size_t)N_EXP*D_FF*D_MODEL;     // 8.39M elems per weight
  const size_t XSZ = (size_t)NTOK*D_MODEL;           // 4.19M
  char* ws = (char*)d_ws;
  size_t off = 0;
  unsigned short* W1b = (unsigned short*)(ws+off); off += WSZ*2;
  unsigned short* V1b = (unsigned short*)(ws+off); size_t v1_off = off; off += WSZ*2;
  unsigned short* Xb  = (unsigned short*)(ws+off); off += XSZ*2;
  unsigned short* G   = (unsigned short*)(ws+off); off += (size_t)NEPAD*D_FF*2;
  int*   etok  = (int*)(ws+off);   size_t entry_off = off; off += (size_t)NEPAD*4;
  float* escl  = (float*)(ws+off); off += (size_t)NEPAD*4;
  size_t entry_bytes = off - entry_off;
  int*   pos   = (int*)(ws+off);   off += (size_t)NTOK*2*4;
  int*   tok_e = (int*)(ws+off);   off += (size_t)NTOK*2*4;
  float* tok_s = (float*)(ws+off); off += (size_t)NTOK*2*4;
  float* Pbins = (float*)(ws+off); size_t pb_off = off; off += 512*4;
  Ctrl*  ctrl  = (Ctrl*)(ws+off);  off += sizeof(Ctrl);
  size_t pb_bytes = off - pb_off;
  // Ye (single): 18432*512*2 = 18.87MB, fits V1b(16.78)+Xb(8.39)=25.17MB dead region
  unsigned short* Ye  = (unsigned short*)(ws+v1_off);
  if(ws_size < off) return;

  // optional dedicated W2 buffer (lets W2 cvt run inside prep, no serial bubble)
  unsigned short* W2d = (unsigned short*)(ws+off);
  bool hoistW2 = (ws_size >= off + WSZ*2);
  unsigned short* W2b = hoistW2 ? W2d : W1b;

  hipMemsetAsync(ws+entry_off, 0, entry_bytes, stream);
  hipMemsetAsync(ws+pb_off, 0, pb_bytes, stream);

  // fused gate + weight-conversions (gate: blocks 0..2047; cvt: 4096 blocks per tensor)
  int nconv = hoistW2 ? 3 : 2;
  prep_kernel<<<2048 + nconv*4096, 256, 0, stream>>>(x, gw, W1, V1, W2, W1b, V1b, W2d,
                                                     tok_e, tok_s, ctrl, Pbins, Xb);
  scan_kernel<<<1, 256, 0, stream>>>(ctrl, Pbins, out);
  scatter_kernel<<<NTOK/256, 256, 0, stream>>>(tok_e, tok_s, ctrl, etok, escl, pos);

  expA_kernel<<<1152, 512, 0, stream>>>(Xb, W1b, V1b, etok, ctrl, G);
  if(!hoistW2)
    cvt_kernel<<<(int)WSZ/(256*8), 256, 0, stream>>>(W2, W1b, (int)WSZ);  // into W1b region
  expB_kernel<<<144, 512, 0, stream>>>(G, W2b, ctrl, Ye);
  combine_kernel<<<NTOK/4, 256, 0, stream>>>(Ye, pos, tok_s, out);
}

// Round 10
// 280.505 us; speedup vs baseline: 1.2751x; 1.1272x over previous
//
#include <hip/hip_runtime.h>
#include <hip/hip_bf16.h>
#include <stdint.h>

#define D_MODEL 512
#define N_EXP 8
#define D_FF 2048
#define NTOK 8192
#define TM 256
#define MAX_TILES 72                 /* ceil(16384/256) + 8 */
#define NEPAD (MAX_TILES*TM)         /* 18432 */
#define BK 64

typedef __attribute__((ext_vector_type(8))) short short8;
typedef __attribute__((ext_vector_type(4))) float f32x4;

struct Ctrl {
  int cnt[8];
  int cursor[8];
  int offpad[16];
  int ntiles;
  int pad[3];
  int texp[MAX_TILES];
};

__device__ __forceinline__ unsigned short f2bf(float f){
  unsigned u = __float_as_uint(f);
  u += 0x7FFFu + ((u>>16)&1u);          // RNE
  return (unsigned short)(u>>16);
}
__device__ __forceinline__ float bf2f(unsigned short v){
  return __uint_as_float(((unsigned)v)<<16);
}

__device__ __forceinline__ short8 pack8(float4 a, float4 b){
  short8 o;
  o[0]=(short)f2bf(a.x); o[1]=(short)f2bf(a.y); o[2]=(short)f2bf(a.z); o[3]=(short)f2bf(a.w);
  o[4]=(short)f2bf(b.x); o[5]=(short)f2bf(b.y); o[6]=(short)f2bf(b.z); o[7]=(short)f2bf(b.w);
  return o;
}

__device__ __forceinline__ void gload16(const void* g, void* l){
  __builtin_amdgcn_global_load_lds((const __attribute__((address_space(1))) unsigned int*)g,
                                   (__attribute__((address_space(3))) unsigned int*)l, 16, 0, 0);
}

#define SBAR0 __builtin_amdgcn_sched_barrier(0)
#define BAR   do{ SBAR0; __builtin_amdgcn_s_barrier(); SBAR0; }while(0)
#define LGKM0 do{ asm volatile("s_waitcnt lgkmcnt(0)" ::: "memory"); SBAR0; }while(0)
#define VM(N) do{ asm volatile("s_waitcnt vmcnt(" #N ")" ::: "memory"); SBAR0; }while(0)

// ---------------- prep: gate (blocks 0..2047) + weight f32->bf16 (rest) ----------------
__global__ void __launch_bounds__(256)
prep_kernel(const float* __restrict__ x, const float* __restrict__ gw,
            const float* __restrict__ W1, const float* __restrict__ V1, const float* __restrict__ W2,
            unsigned short* __restrict__ W1b, unsigned short* __restrict__ V1b, unsigned short* __restrict__ W2d,
            int* __restrict__ tok_e, float* __restrict__ tok_s,
            Ctrl* __restrict__ c, float* __restrict__ Pbins,
            unsigned short* __restrict__ Xb){
  __shared__ float gws[N_EXP*D_MODEL];
  __shared__ float pblk[4][8];
  __shared__ int cblk[8];
  int bid = blockIdx.x;
  int tid = threadIdx.x;
  if(bid >= 2048){
    int j = bid - 2048;
    const float* src = (j<4096) ? W1 : (j<8192 ? V1 : W2);
    unsigned short* dst = (j<4096) ? W1b : (j<8192 ? V1b : W2d);
    int i = (j & 4095)*2048 + tid*8;
    float4 a = *(const float4*)(src+i);
    float4 b = *(const float4*)(src+i+4);
    *(short8*)(dst+i) = pack8(a,b);
    return;
  }
  for(int i=tid; i<N_EXP*D_MODEL; i+=256) gws[i]=gw[i];
  if(tid<8) cblk[tid]=0;
  __syncthreads();
  int wave = tid>>6, lane = tid&63;
  int t = bid*4 + wave;
  const float* xr = x + (size_t)t*D_MODEL + lane*8;
  float4 xa = *(const float4*)xr;
  float4 xb = *(const float4*)(xr+4);
  *(short8*)(Xb + (size_t)t*D_MODEL + lane*8) = pack8(xa,xb);
  float le[8];
  #pragma unroll
  for(int e=0;e<8;e++){
    const float* g = gws + e*D_MODEL + lane*8;
    float4 ga = *(const float4*)g;
    float4 gb = *(const float4*)(g+4);
    le[e] = xa.x*ga.x + xa.y*ga.y + xa.z*ga.z + xa.w*ga.w
          + xb.x*gb.x + xb.y*gb.y + xb.z*gb.z + xb.w*gb.w;
  }
  #pragma unroll
  for(int e=0;e<8;e++){
    float v = le[e];
    #pragma unroll
    for(int off=1; off<64; off<<=1) v += __shfl_xor(v, off);
    le[e]=v;
  }
  float mx = le[0];
  #pragma unroll
  for(int e=1;e<8;e++) mx = fmaxf(mx, le[e]);
  float p[8], s=0.f;
  #pragma unroll
  for(int e=0;e<8;e++){ p[e]=__expf(le[e]-mx); s+=p[e]; }
  float inv = 1.0f/s;
  #pragma unroll
  for(int e=0;e<8;e++) p[e]*=inv;
  int e0=0; float s0=p[0];
  #pragma unroll
  for(int e=1;e<8;e++) if(p[e]>s0){e0=e;s0=p[e];}
  int e1=-1; float s1=-1.f;
  #pragma unroll
  for(int e=0;e<8;e++) if(e!=e0 && p[e]>s1){e1=e;s1=p[e];}
  if(lane==0){
    tok_e[2*t]=e0; tok_e[2*t+1]=e1;
    tok_s[2*t]=s0; tok_s[2*t+1]=s1;
    atomicAdd(&cblk[e0],1); atomicAdd(&cblk[e1],1);
    #pragma unroll
    for(int e=0;e<8;e++) pblk[wave][e]=p[e];
  }
  __syncthreads();
  if(tid<8){
    atomicAdd(&c->cnt[tid], cblk[tid]);
    atomicAdd(&Pbins[(bid&63)*8 + tid],
              pblk[0][tid]+pblk[1][tid]+pblk[2][tid]+pblk[3][tid]);
  }
}

__global__ void __launch_bounds__(256)
cvt_kernel(const float* __restrict__ src, unsigned short* __restrict__ dst, int n){
  int i = (blockIdx.x*256 + threadIdx.x)*8;
  if(i >= n) return;
  float4 a = *(const float4*)(src+i);
  float4 b = *(const float4*)(src+i+4);
  *(short8*)(dst+i) = pack8(a,b);
}

// ---------------- scatter (+ block0: ctrl fill + aux loss) ----------------
__global__ void __launch_bounds__(256)
scatter_kernel(const int* __restrict__ tok_e, const float* __restrict__ tok_s,
               Ctrl* __restrict__ c, int* __restrict__ etok, float* __restrict__ escl,
               int* __restrict__ pos, const float* __restrict__ Pbins, float* __restrict__ out){
  __shared__ int soff[8];
  __shared__ float pred[4][8];
  int tid = threadIdx.x;
  if(tid==0){
    int o=0;
    #pragma unroll
    for(int e=0;e<8;e++){ soff[e]=o; o += ((c->cnt[e]+TM-1)/TM)*TM; }
  }
  __syncthreads();
  int t = blockIdx.x*256 + tid;
  #pragma unroll
  for(int k=0;k<2;k++){
    int e = tok_e[2*t+k];
    int p = atomicAdd(&c->cursor[e],1);
    int i = soff[e]+p;
    etok[i]=t; escl[i]=tok_s[2*t+k];
    pos[2*t+k]=i;
  }
  if(blockIdx.x==0){
    float v = Pbins[tid] + Pbins[tid+256];   // 512 bins = 64 x 8 experts
    v += __shfl_xor(v, 8);
    v += __shfl_xor(v, 16);
    v += __shfl_xor(v, 32);
    if((tid&63)<8) pred[tid>>6][tid&7] = v;
    __syncthreads();
    if(tid==0){
      int o=0, tc=0;
      float aux=0.f;
      #pragma unroll
      for(int e=0;e<8;e++){
        float tot = pred[0][e]+pred[1][e]+pred[2][e]+pred[3][e];
        c->offpad[e]=o;
        int nt = (c->cnt[e]+TM-1)/TM;
        for(int i=0;i<nt;i++) c->texp[tc++]=e;
        o += nt*TM;
        aux += ((float)c->cnt[e]/(float)NTOK) * (tot/(float)NTOK);
      }
      c->offpad[8]=o;
      c->ntiles=tc;
      out[(size_t)NTOK*D_MODEL] = 8.0f*0.01f*aux;
    }
  }
}

// ---------------- phase A: G = silu(X W1^T) * (X V1^T) ----------------
// tile 256 x (128 W + 128 V). 8 waves 2Mx4N, wave = 128r x 64effc.
// 2-barrier K-tile: {ph1-3 reads+MFMA barrier-free} -> LGKM0+BAR -> stage-all(k+2,cur)
// -> ph4 MFMA (reg-only) -> VM(8) -> BAR. Depth-2 prefetch, 0.375 reads/MFMA.
__global__ void __launch_bounds__(512,2)
expA_kernel(const unsigned short* __restrict__ Xb, const unsigned short* __restrict__ W1b,
            const unsigned short* __restrict__ V1b, const int* __restrict__ etok,
            const Ctrl* __restrict__ c, unsigned short* __restrict__ G){
  __shared__ short8 As[2][2048];   // [par][row*8 + swz chunk], rows 0-255
  __shared__ short8 Bs[2][2048];   // [par][W rows 0-127 | V rows 0-127]
  int bid = blockIdx.x;                  // 1152 = 8 XCD-chunks * 144
  int chunk = bid & 7;
  int w_in = bid >> 3;                   // fb-outer, tile-inner (B-panel L2 reuse)
  int fb = w_in / 9;
  int tile = chunk*9 + (w_in - fb*9);
  int fbase = fb * 128;
  if(tile >= c->ntiles) return;
  int e = c->texp[tile];
  int base = tile*TM;
  int tid = threadIdx.x;

  int r0 = tid>>3;
  int cs = (tid&7) ^ (r0&7);             // inverse-swizzled global source chunk
  int t0 = etok[base + r0] & (NTOK-1);   // mask: padding entries may be poison
  int t1 = etok[base + 64 + r0] & (NTOK-1);
  int t2 = etok[base + 128 + r0] & (NTOK-1);
  int t3 = etok[base + 192 + r0] & (NTOK-1);
  const unsigned short* sA0 = Xb + (size_t)t0*D_MODEL + cs*8;
  const unsigned short* sA1 = Xb + (size_t)t1*D_MODEL + cs*8;
  const unsigned short* sA2 = Xb + (size_t)t2*D_MODEL + cs*8;
  const unsigned short* sA3 = Xb + (size_t)t3*D_MODEL + cs*8;
  const unsigned short* WE = W1b + (size_t)e*(D_FF*D_MODEL);
  const unsigned short* VE = V1b + (size_t)e*(D_FF*D_MODEL);
  const unsigned short* sB0 = WE + (size_t)(fbase+r0)*D_MODEL + cs*8;
  const unsigned short* sB1 = WE + (size_t)(fbase+64+r0)*D_MODEL + cs*8;
  const unsigned short* sB2 = VE + (size_t)(fbase+r0)*D_MODEL + cs*8;
  const unsigned short* sB3 = VE + (size_t)(fbase+64+r0)*D_MODEL + cs*8;
  int w64 = tid & ~63;

  int lane = tid&63, lrow = lane&15, lk = lane>>4;
  int wid = tid>>6, wr = wid>>2, wc = wid&3;
  int sw = lrow&7;
  int ch0 = lk ^ sw;
  int ch1 = (4+lk) ^ sw;

  f32x4 hacc[8][2], vacc[8][2];
  #pragma unroll
  for(int mi=0;mi<8;mi++)
    #pragma unroll
    for(int nj=0;nj<2;nj++){
      hacc[mi][nj]=(f32x4){0.f,0.f,0.f,0.f};
      vacc[mi][nj]=(f32x4){0.f,0.f,0.f,0.f};
    }

  auto ST_ALL = [&](int b, int kt){      // 8 gloads per wave
    size_t o=(size_t)kt*BK;
    gload16(sA0+o, &As[b][w64]);      gload16(sA1+o, &As[b][512+w64]);
    gload16(sA2+o, &As[b][1024+w64]); gload16(sA3+o, &As[b][1536+w64]);
    gload16(sB0+o, &Bs[b][w64]);      gload16(sB1+o, &Bs[b][512+w64]);
    gload16(sB2+o, &Bs[b][1024+w64]); gload16(sB3+o, &Bs[b][1536+w64]);
  };

  // prologue: k=0 -> buf0, k=1 -> buf1 (16 loads); VM(8) completes k=0.
  ST_ALL(0,0);
  ST_ALL(1,1);
  VM(8);
  BAR;

  short8 alo[4][2], ahi[4][2], bw[2][2], bv[2][2];

  #pragma unroll
  for(int k=0;k<8;k++){
    const int cur = k&1;
    // ---- ph1: A-lo + W -> hacc lo ----
    #pragma unroll
    for(int j=0;j<4;j++){
      int s = (wr*128 + j*16 + lrow)*8;
      alo[j][0] = As[cur][s + ch0];
      alo[j][1] = As[cur][s + ch1];
    }
    #pragma unroll
    for(int nj=0;nj<2;nj++){
      int s = (wc*32 + nj*16 + lrow)*8;
      bw[nj][0] = Bs[cur][s + ch0];
      bw[nj][1] = Bs[cur][s + ch1];
    }
    __builtin_amdgcn_s_setprio(1);
    #pragma unroll
    for(int j=0;j<4;j++)
      #pragma unroll
      for(int nj=0;nj<2;nj++){
        hacc[j][nj] = __builtin_amdgcn_mfma_f32_16x16x32_bf16(alo[j][0], bw[nj][0], hacc[j][nj],0,0,0);
        hacc[j][nj] = __builtin_amdgcn_mfma_f32_16x16x32_bf16(alo[j][1], bw[nj][1], hacc[j][nj],0,0,0);
      }
    __builtin_amdgcn_s_setprio(0);
    // ---- ph2: V -> vacc lo ----
    #pragma unroll
    for(int nj=0;nj<2;nj++){
      int s = 1024 + (wc*32 + nj*16 + lrow)*8;
      bv[nj][0] = Bs[cur][s + ch0];
      bv[nj][1] = Bs[cur][s + ch1];
    }
    __builtin_amdgcn_s_setprio(1);
    #pragma unroll
    for(int j=0;j<4;j++)
      #pragma unroll
      for(int nj=0;nj<2;nj++){
        vacc[j][nj] = __builtin_amdgcn_mfma_f32_16x16x32_bf16(alo[j][0], bv[nj][0], vacc[j][nj],0,0,0);
        vacc[j][nj] = __builtin_amdgcn_mfma_f32_16x16x32_bf16(alo[j][1], bv[nj][1], vacc[j][nj],0,0,0);
      }
    __builtin_amdgcn_s_setprio(0);
    // ---- ph3: A-hi -> vacc hi ----
    #pragma unroll
    for(int j=0;j<4;j++){
      int s = (wr*128 + 64 + j*16 + lrow)*8;
      ahi[j][0] = As[cur][s + ch0];
      ahi[j][1] = As[cur][s + ch1];
    }
    __builtin_amdgcn_s_setprio(1);
    #pragma unroll
    for(int j=0;j<4;j++)
      #pragma unroll
      for(int nj=0;nj<2;nj++){
        vacc[4+j][nj] = __builtin_amdgcn_mfma_f32_16x16x32_bf16(ahi[j][0], bv[nj][0], vacc[4+j][nj],0,0,0);
        vacc[4+j][nj] = __builtin_amdgcn_mfma_f32_16x16x32_bf16(ahi[j][1], bv[nj][1], vacc[4+j][nj],0,0,0);
      }
    __builtin_amdgcn_s_setprio(0);
    // ---- drain + barrier; stage all of k+2 into cur; ph4 (reg-only) ----
    LGKM0;
    BAR;
    if(k<6) ST_ALL(cur, k+2);
    __builtin_amdgcn_s_setprio(1);
    #pragma unroll
    for(int j=0;j<4;j++)
      #pragma unroll
      for(int nj=0;nj<2;nj++){
        hacc[4+j][nj] = __builtin_amdgcn_mfma_f32_16x16x32_bf16(ahi[j][0], bw[nj][0], hacc[4+j][nj],0,0,0);
        hacc[4+j][nj] = __builtin_amdgcn_mfma_f32_16x16x32_bf16(ahi[j][1], bw[nj][1], hacc[4+j][nj],0,0,0);
      }
    __builtin_amdgcn_s_setprio(0);
    if(k<6){ VM(8); } else if(k==6){ VM(0); }
    BAR;
  }

  #pragma unroll
  for(int mi=0;mi<8;mi++){
    int m = base + wr*128 + mi*16 + lk*4;
    #pragma unroll
    for(int nj=0;nj<2;nj++){
      int f = fbase + wc*32 + nj*16 + lrow;
      #pragma unroll
      for(int r=0;r<4;r++){
        float h = hacc[mi][nj][r], vv = vacc[mi][nj][r];
        float g = (h/(1.0f+__expf(-h)))*vv;
        G[(size_t)(m+r)*D_FF + f] = f2bf(g);
      }
    }
  }
}

// ---------------- phase B: Ye = G W2^T (per-entry rows, no atomics) ----------------
// tile 256 entries x 256 n-cols (nb 2), K=2048 -> 32 K-tiles. Same 2-barrier template.
__global__ void __launch_bounds__(512,2)
expB_kernel(const unsigned short* __restrict__ G, const unsigned short* __restrict__ W2b,
            const Ctrl* __restrict__ c, unsigned short* __restrict__ Ye){
  __shared__ short8 As2[2][2048];  // 256 rows x 8 chunks
  __shared__ short8 Bs2[2][2048];  // 256 rows x 8 chunks
  int bid = blockIdx.x;                 // 144 = 8*18
  int w = (bid & 7)*18 + (bid >> 3);    // XCD-chunked bijective swizzle
  int tile = w >> 1;
  int nb = w & 1;
  if(tile >= c->ntiles) return;
  int e = c->texp[tile];
  int base = tile*TM;
  int nbase = nb*256;
  int tid = threadIdx.x;

  int r0 = tid>>3;
  int cs = (tid&7) ^ (r0&7);
  const unsigned short* sA0 = G + (size_t)(base+r0)*D_FF + cs*8;
  const unsigned short* sA1 = G + (size_t)(base+64+r0)*D_FF + cs*8;
  const unsigned short* sA2 = G + (size_t)(base+128+r0)*D_FF + cs*8;
  const unsigned short* sA3 = G + (size_t)(base+192+r0)*D_FF + cs*8;
  const unsigned short* W2E = W2b + (size_t)e*(D_MODEL*D_FF);
  const unsigned short* sB0 = W2E + (size_t)(nbase+r0)*D_FF + cs*8;
  const unsigned short* sB1 = W2E + (size_t)(nbase+64+r0)*D_FF + cs*8;
  const unsigned short* sB2 = W2E + (size_t)(nbase+128+r0)*D_FF + cs*8;
  const unsigned short* sB3 = W2E + (size_t)(nbase+192+r0)*D_FF + cs*8;
  int w64 = tid & ~63;

  int lane = tid&63, lrow = lane&15, lk = lane>>4;
  int wid = tid>>6, wr = wid>>2, wc = wid&3;
  int sw = lrow&7;
  int ch0 = lk ^ sw;
  int ch1 = (4+lk) ^ sw;

  f32x4 acc[8][4];
  #pragma unroll
  for(int mi=0;mi<8;mi++)
    #pragma unroll
    for(int nj=0;nj<4;nj++) acc[mi][nj]=(f32x4){0.f,0.f,0.f,0.f};

  auto ST_ALL = [&](int b, int kt){
    size_t o=(size_t)kt*BK;
    gload16(sA0+o, &As2[b][w64]);      gload16(sA1+o, &As2[b][512+w64]);
    gload16(sA2+o, &As2[b][1024+w64]); gload16(sA3+o, &As2[b][1536+w64]);
    gload16(sB0+o, &Bs2[b][w64]);      gload16(sB1+o, &Bs2[b][512+w64]);
    gload16(sB2+o, &Bs2[b][1024+w64]); gload16(sB3+o, &Bs2[b][1536+w64]);
  };

  ST_ALL(0,0);
  ST_ALL(1,1);
  VM(8);
  BAR;

  short8 alo[4][2], ahi[4][2], bl[2][2], bh[2][2];

  #pragma unroll 2
  for(int k=0;k<32;k++){
    const int cur = k&1;
    // ---- ph1: A-lo + B-lo ----
    #pragma unroll
    for(int j=0;j<4;j++){
      int s = (wr*128 + j*16 + lrow)*8;
      alo[j][0] = As2[cur][s + ch0];
      alo[j][1] = As2[cur][s + ch1];
    }
    #pragma unroll
    for(int nj=0;nj<2;nj++){
      int s = (wc*64 + nj*16 + lrow)*8;
      bl[nj][0] = Bs2[cur][s + ch0];
      bl[nj][1] = Bs2[cur][s + ch1];
    }
    __builtin_amdgcn_s_setprio(1);
    #pragma unroll
    for(int j=0;j<4;j++)
      #pragma unroll
      for(int nj=0;nj<2;nj++){
        acc[j][nj] = __builtin_amdgcn_mfma_f32_16x16x32_bf16(alo[j][0], bl[nj][0], acc[j][nj],0,0,0);
        acc[j][nj] = __builtin_amdgcn_mfma_f32_16x16x32_bf16(alo[j][1], bl[nj][1], acc[j][nj],0,0,0);
      }
    __builtin_amdgcn_s_setprio(0);
    // ---- ph2: B-hi ----
    #pragma unroll
    for(int nj=0;nj<2;nj++){
      int s = (wc*64 + 32 + nj*16 + lrow)*8;
      bh[nj][0] = Bs2[cur][s + ch0];
      bh[nj][1] = Bs2[cur][s + ch1];
    }
    __builtin_amdgcn_s_setprio(1);
    #pragma unroll
    for(int j=0;j<4;j++)
      #pragma unroll
      for(int nj=0;nj<2;nj++){
        acc[j][2+nj] = __builtin_amdgcn_mfma_f32_16x16x32_bf16(alo[j][0], bh[nj][0], acc[j][2+nj],0,0,0);
        acc[j][2+nj] = __builtin_amdgcn_mfma_f32_16x16x32_bf16(alo[j][1], bh[nj][1], acc[j][2+nj],0,0,0);
      }
    __builtin_amdgcn_s_setprio(0);
    // ---- ph3: A-hi ----
    #pragma unroll
    for(int j=0;j<4;j++){
      int s = (wr*128 + 64 + j*16 + lrow)*8;
      ahi[j][0] = As2[cur][s + ch0];
      ahi[j][1] = As2[cur][s + ch1];
    }
    __builtin_amdgcn_s_setprio(1);
    #pragma unroll
    for(int j=0;j<4;j++)
      #pragma unroll
      for(int nj=0;nj<2;nj++){
        acc[4+j][2+nj] = __builtin_amdgcn_mfma_f32_16x16x32_bf16(ahi[j][0], bh[nj][0], acc[4+j][2+nj],0,0,0);
        acc[4+j][2+nj] = __builtin_amdgcn_mfma_f32_16x16x32_bf16(ahi[j][1], bh[nj][1], acc[4+j][2+nj],0,0,0);
      }
    __builtin_amdgcn_s_setprio(0);
    // ---- drain + barrier; stage k+2 into cur; ph4 reg-only ----
    LGKM0;
    BAR;
    if(k<30) ST_ALL(cur, k+2);
    __builtin_amdgcn_s_setprio(1);
    #pragma unroll
    for(int j=0;j<4;j++)
      #pragma unroll
      for(int nj=0;nj<2;nj++){
        acc[4+j][nj] = __builtin_amdgcn_mfma_f32_16x16x32_bf16(ahi[j][0], bl[nj][0], acc[4+j][nj],0,0,0);
        acc[4+j][nj] = __builtin_amdgcn_mfma_f32_16x16x32_bf16(ahi[j][1], bl[nj][1], acc[4+j][nj],0,0,0);
      }
    __builtin_amdgcn_s_setprio(0);
    if(k<30){ VM(8); } else if(k==30){ VM(0); }
    BAR;
  }

  #pragma unroll
  for(int mi=0;mi<8;mi++){
    #pragma unroll
    for(int r=0;r<4;r++){
      int m = base + wr*128 + mi*16 + lk*4 + r;
      #pragma unroll
      for(int nj=0;nj<4;nj++){
        int n = nbase + wc*64 + nj*16 + lrow;
        Ye[(size_t)m*D_MODEL + n] = f2bf(acc[mi][nj][r]);
      }
    }
  }
}

// ---------------- combine: out[t] = s0*Ye[p0] + s1*Ye[p1] ----------------
__global__ void __launch_bounds__(256)
combine_kernel(const unsigned short* __restrict__ Ye, const int* __restrict__ pos,
               const float* __restrict__ tok_s, float* __restrict__ out){
  int wave = threadIdx.x>>6, lane = threadIdx.x&63;
  int t = blockIdx.x*4 + wave;
  int p0 = pos[2*t], p1 = pos[2*t+1];
  float s0 = tok_s[2*t], s1 = tok_s[2*t+1];
  short8 y0 = *(const short8*)(Ye + (size_t)p0*D_MODEL + lane*8);
  short8 y1 = *(const short8*)(Ye + (size_t)p1*D_MODEL + lane*8);
  float* o = out + (size_t)t*D_MODEL + lane*8;
  float v[8];
  #pragma unroll
  for(int i=0;i<8;i++)
    v[i] = s0*bf2f((unsigned short)y0[i]) + s1*bf2f((unsigned short)y1[i]);
  float4 lo = {v[0],v[1],v[2],v[3]};
  float4 hi = {v[4],v[5],v[6],v[7]};
  *(float4*)o = lo;
  *(float4*)(o+4) = hi;
}

extern "C" void kernel_launch(void* const* d_in, const int* in_sizes, int n_in,
                              void* d_out, int out_size, void* d_ws, size_t ws_size,
                              hipStream_t stream) {
  (void)in_sizes; (void)n_in; (void)out_size;
  const float* x  = (const float*)d_in[0];
  const float* gw = (const float*)d_in[1];
  const float* W1 = (const float*)d_in[2];
  const float* V1 = (const float*)d_in[3];
  const float* W2 = (const float*)d_in[4];
  float* out = (float*)d_out;

  const size_t WSZ = (size_t)N_EXP*D_FF*D_MODEL;     // 8.39M elems per weight
  const size_t XSZ = (size_t)NTOK*D_MODEL;           // 4.19M
  char* ws = (char*)d_ws;
  size_t off = 0;
  unsigned short* W1b = (unsigned short*)(ws+off); off += WSZ*2;
  unsigned short* V1b = (unsigned short*)(ws+off); size_t v1_off = off; off += WSZ*2;
  unsigned short* Xb  = (unsigned short*)(ws+off); off += XSZ*2;
  unsigned short* G   = (unsigned short*)(ws+off); off += (size_t)NEPAD*D_FF*2;
  int*   etok  = (int*)(ws+off);   off += (size_t)NEPAD*4;
  float* escl  = (float*)(ws+off); off += (size_t)NEPAD*4;
  int*   pos   = (int*)(ws+off);   off += (size_t)NTOK*2*4;
  int*   tok_e = (int*)(ws+off);   off += (size_t)NTOK*2*4;
  float* tok_s = (float*)(ws+off); off += (size_t)NTOK*2*4;
  float* Pbins = (float*)(ws+off); size_t pb_off = off; off += 512*4;
  Ctrl*  ctrl  = (Ctrl*)(ws+off);  off += sizeof(Ctrl);
  size_t pb_bytes = off - pb_off;
  // Ye (single): 18432*512*2 = 18.87MB, fits V1b(16.78)+Xb(8.39)=25.17MB dead region
  unsigned short* Ye  = (unsigned short*)(ws+v1_off);
  if(ws_size < off) return;

  // optional dedicated W2 buffer (lets W2 cvt run inside prep, no serial bubble)
  unsigned short* W2d = (unsigned short*)(ws+off);
  bool hoistW2 = (ws_size >= off + WSZ*2);
  unsigned short* W2b = hoistW2 ? W2d : W1b;

  hipMemsetAsync(ws+pb_off, 0, pb_bytes, stream);   // Pbins + ctrl (cnt/cursor zeroed)

  int nconv = hoistW2 ? 3 : 2;
  prep_kernel<<<2048 + nconv*4096, 256, 0, stream>>>(x, gw, W1, V1, W2, W1b, V1b, W2d,
                                                     tok_e, tok_s, ctrl, Pbins, Xb);
  scatter_kernel<<<NTOK/256, 256, 0, stream>>>(tok_e, tok_s, ctrl, etok, escl, pos, Pbins, out);

  expA_kernel<<<1152, 512, 0, stream>>>(Xb, W1b, V1b, etok, ctrl, G);
  if(!hoistW2)
    cvt_kernel<<<(int)WSZ/(256*8), 256, 0, stream>>>(W2, W1b, (int)WSZ);  // into W1b region
  expB_kernel<<<144, 512, 0, stream>>>(G, W2b, ctrl, Ye);
  combine_kernel<<<NTOK/4, 256, 0, stream>>>(Ye, pos, tok_s, out);
}